// Round 5
// baseline (499.479 us; speedup 1.0000x reference)
//
#include <hip/hip_runtime.h>
#include <stdint.h>

// MultiHeadAttention  b=4, L=2048, d=1024, H=16, dk=64. I/O fp32; bf16/f16 MFMA inside.
#define D_MODEL 1024
#define NHEADS 16
#define DKH 64
#define SEQ 2048
#define BATCH 4
#define M_TOT (BATCH * SEQ) // 8192
#define LOG2E 1.44269504088896340736f

typedef __bf16 v8bf __attribute__((ext_vector_type(8)));
typedef __bf16 v4bf __attribute__((ext_vector_type(4)));
typedef _Float16 v8h __attribute__((ext_vector_type(8)));
typedef _Float16 v4h __attribute__((ext_vector_type(4)));
typedef float v4f __attribute__((ext_vector_type(4)));

typedef const __attribute__((address_space(1))) void* gas_ptr;
typedef __attribute__((address_space(3))) void* las_ptr;

static __device__ __forceinline__ void async16(const void* g, void* l) {
    __builtin_amdgcn_global_load_lds((gas_ptr)g, (las_ptr)l, 16, 0, 0);
}

static __device__ __forceinline__ v4f mfma16x32(v8bf a, v8bf b, v4f c) {
    // D(16x16)=A(16x32)*B(32x16)+C. A: m=l&15,k=(l>>4)*8+j. B: k=(l>>4)*8+j,n=l&15.
    // D: col=l&15, row=(l>>4)*4+reg.   (verified R2-R4)
    return __builtin_amdgcn_mfma_f32_16x16x32_bf16(a, b, c, 0, 0, 0);
}
static __device__ __forceinline__ v4f mfma16x16h(v4h a, v4h b, v4f c) {
    // D(16x16)=A(16x16)*B(16x16)+C. A: m=l&15,k=(l>>4)*4+j. B: k=(l>>4)*4+j,n=l&15.
    return __builtin_amdgcn_mfma_f32_16x16x16f16(a, b, c, 0, 0, 0);
}

// Convert 4 fp32 weight matrices to packed bf16 [4][1024*1024]
__global__ __launch_bounds__(256) void cvt_w(const float* __restrict__ w0,
                                             const float* __restrict__ w1,
                                             const float* __restrict__ w2,
                                             const float* __restrict__ w3,
                                             __bf16* __restrict__ dst) {
    int gid = blockIdx.x * 256 + threadIdx.x;
    int tsel = gid >> 17;
    int off = gid & 131071;
    const float* s = (tsel == 0) ? w0 : (tsel == 1) ? w1 : (tsel == 2) ? w2 : w3;
    const float4* sp = (const float4*)s + 2 * (size_t)off;
    float4 a = sp[0], b = sp[1];
    v8bf o;
    o[0] = (__bf16)a.x; o[1] = (__bf16)a.y; o[2] = (__bf16)a.z; o[3] = (__bf16)a.w;
    o[4] = (__bf16)b.x; o[5] = (__bf16)b.y; o[6] = (__bf16)b.z; o[7] = (__bf16)b.w;
    *(v8bf*)(dst + ((size_t)tsel << 20) + (size_t)off * 8) = o;
}

// Fused QKV projection. z=0:Q (scale folded), z=1:K, z=2:V written transposed f16
// with key-permuted layout (quad-interleaved per 32-key block) for 16B attn loads.
__global__ __launch_bounds__(256) void gemm_qkv(const float* __restrict__ Q,
                                                const float* __restrict__ K,
                                                const float* __restrict__ V,
                                                const __bf16* __restrict__ Wb,
                                                __bf16* __restrict__ qh,
                                                __bf16* __restrict__ kh,
                                                _Float16* __restrict__ vt) {
    const int t = threadIdx.x, lane = t & 63, wave = t >> 6;
    const int r = lane & 15, qd = lane >> 4;
    const int z = blockIdx.z;
    const int m0 = blockIdx.x * 128, n0 = blockIdx.y * 128;
    const int mw = (wave & 1) * 64, nw = (wave >> 1) * 64;
    const float* A = (z == 0) ? Q : (z == 1) ? K : V;
    const __bf16* W = Wb + ((size_t)z << 20);

    __shared__ __align__(16) __bf16 As[128 * 32];
    __shared__ __align__(16) __bf16 Bs[128 * 32];

    const int arow = t >> 1, ak = (t & 1) * 16;
    const float* ag = A + (size_t)(m0 + arow) * D_MODEL + ak;
    const int aswz = (arow >> 1) & 3;
    const int p0 = ((t & 1) * 2) ^ aswz, p1 = ((t & 1) * 2 + 1) ^ aswz;
    const int wc = (lane & 3) ^ ((lane >> 3) & 3);
    const int wrow = lane >> 2;
    const int rdpos = (qd ^ ((r >> 1) & 3)) * 8;

    v4f acc[4][4] = {};
    for (int k0 = 0; k0 < D_MODEL; k0 += 32) {
#pragma unroll
        for (int p = 0; p < 2; ++p) {
            int rb = (p * 4 + wave) * 16;
            async16(W + (size_t)(n0 + rb + wrow) * D_MODEL + k0 + wc * 8, &Bs[rb * 32]);
        }
        float4 f0 = *(const float4*)(ag + k0);
        float4 f1 = *(const float4*)(ag + k0 + 4);
        float4 f2 = *(const float4*)(ag + k0 + 8);
        float4 f3 = *(const float4*)(ag + k0 + 12);
        v8bf b0, b1;
        b0[0] = (__bf16)f0.x; b0[1] = (__bf16)f0.y; b0[2] = (__bf16)f0.z; b0[3] = (__bf16)f0.w;
        b0[4] = (__bf16)f1.x; b0[5] = (__bf16)f1.y; b0[6] = (__bf16)f1.z; b0[7] = (__bf16)f1.w;
        b1[0] = (__bf16)f2.x; b1[1] = (__bf16)f2.y; b1[2] = (__bf16)f2.z; b1[3] = (__bf16)f2.w;
        b1[4] = (__bf16)f3.x; b1[5] = (__bf16)f3.y; b1[6] = (__bf16)f3.z; b1[7] = (__bf16)f3.w;
        *(v8bf*)&As[arow * 32 + p0 * 8] = b0;
        *(v8bf*)&As[arow * 32 + p1 * 8] = b1;
        __syncthreads();
        v8bf af[4], bfr[4];
#pragma unroll
        for (int mt = 0; mt < 4; ++mt)
            af[mt] = *(const v8bf*)&As[(mw + mt * 16 + r) * 32 + rdpos];
#pragma unroll
        for (int nt = 0; nt < 4; ++nt)
            bfr[nt] = *(const v8bf*)&Bs[(nw + nt * 16 + r) * 32 + rdpos];
#pragma unroll
        for (int mt = 0; mt < 4; ++mt)
#pragma unroll
            for (int nt = 0; nt < 4; ++nt)
                acc[mt][nt] = mfma16x32(af[mt], bfr[nt], acc[mt][nt]);
        __syncthreads();
    }

    const float sc = (z == 0) ? 0.125f * LOG2E : 1.0f;
#pragma unroll
    for (int mt = 0; mt < 4; ++mt)
#pragma unroll
        for (int nt = 0; nt < 4; ++nt) {
            int row = m0 + mw + mt * 16 + qd * 4;
            int col = n0 + nw + nt * 16 + r;
            int bb = row >> 11, l = row & (SEQ - 1);
            int h = col >> 6, d = col & (DKH - 1);
            if (z == 2) {
                // permuted key position: pos = (l&~31) + quad*8 + half*4 (+off)
                int pos = (l & ~31) + (((l >> 2) & 3) << 3) + (((l >> 4) & 1) << 2);
                v4h o;
#pragma unroll
                for (int i = 0; i < 4; ++i) o[i] = (_Float16)acc[mt][nt][i];
                *(v4h*)&vt[((size_t)((bb * NHEADS + h) * DKH + d)) * SEQ + pos] = o;
            } else {
                __bf16* dst = (z == 0) ? qh : kh;
#pragma unroll
                for (int i = 0; i < 4; ++i)
                    dst[(((size_t)(bb * NHEADS + h) * SEQ) + l + i) * DKH + d] =
                        (__bf16)(acc[mt][nt][i] * sc);
            }
        }
}

// Output GEMM: C[m,n] = sum_k A[m,k]*W[n,k], A bf16 oh [8192][1024], C fp32.
__global__ __launch_bounds__(256) void gemm_out(const __bf16* __restrict__ A,
                                                const __bf16* __restrict__ W,
                                                float* __restrict__ C) {
    const int t = threadIdx.x, lane = t & 63, wave = t >> 6;
    const int r = lane & 15, qd = lane >> 4;
    const int m0 = blockIdx.x * 128, n0 = blockIdx.y * 128;
    const int mw = (wave & 1) * 64, nw = (wave >> 1) * 64;

    __shared__ __align__(16) __bf16 As[128 * 32];
    __shared__ __align__(16) __bf16 Bs[128 * 32];

    const int wc = (lane & 3) ^ ((lane >> 3) & 3);
    const int wrow = lane >> 2;
    const int rdpos = (qd ^ ((r >> 1) & 3)) * 8;

    v4f acc[4][4] = {};
    for (int k0 = 0; k0 < D_MODEL; k0 += 32) {
#pragma unroll
        for (int p = 0; p < 2; ++p) {
            int rb = (p * 4 + wave) * 16;
            async16(A + (size_t)(m0 + rb + wrow) * D_MODEL + k0 + wc * 8, &As[rb * 32]);
            async16(W + (size_t)(n0 + rb + wrow) * D_MODEL + k0 + wc * 8, &Bs[rb * 32]);
        }
        __syncthreads();
        v8bf af[4], bfr[4];
#pragma unroll
        for (int mt = 0; mt < 4; ++mt)
            af[mt] = *(const v8bf*)&As[(mw + mt * 16 + r) * 32 + rdpos];
#pragma unroll
        for (int nt = 0; nt < 4; ++nt)
            bfr[nt] = *(const v8bf*)&Bs[(nw + nt * 16 + r) * 32 + rdpos];
#pragma unroll
        for (int mt = 0; mt < 4; ++mt)
#pragma unroll
            for (int nt = 0; nt < 4; ++nt)
                acc[mt][nt] = mfma16x32(af[mt], bfr[nt], acc[mt][nt]);
        __syncthreads();
    }
#pragma unroll
    for (int mt = 0; mt < 4; ++mt)
#pragma unroll
        for (int nt = 0; nt < 4; ++nt) {
            int row = m0 + mw + mt * 16 + qd * 4;
            int col = n0 + nw + nt * 16 + r;
#pragma unroll
            for (int i = 0; i < 4; ++i)
                C[(size_t)(row + i) * D_MODEL + col] = acc[mt][nt][i];
        }
}

// Attention: barrier-free, LDS-free. 1024 blocks (XCD swizzle: 8 bh per XCD ->
// K/V L2-resident), 4 waves x 32 queries. K/V fragments register-resident with a
// 2-stage software pipeline (loads for k0+32 issued before compute on k0); no
// __syncthreads -> no vmcnt(0) drains, waves free-run. V is key-permuted so one
// 16B v8h load yields both 16x16x16 A-fragments.
__global__ __launch_bounds__(256, 3) void attn_kernel(const __bf16* __restrict__ qh,
                                                      const __bf16* __restrict__ kh,
                                                      const _Float16* __restrict__ vt,
                                                      __bf16* __restrict__ oh) {
    const int lane = threadIdx.x & 63, wave = threadIdx.x >> 6;
    const int r = lane & 15, qd = lane >> 4;
    const int id = blockIdx.x;
    const int bh = (id & 7) * 8 + ((id >> 3) & 7);
    const int q0 = (id >> 6) * 128 + wave * 32;

    const __bf16* kbh = kh + (size_t)bh * SEQ * DKH;
    const _Float16* vbh = vt + (size_t)bh * DKH * SEQ;

    v8bf qf[2][2];
#pragma unroll
    for (int a = 0; a < 2; ++a) {
        const __bf16* qp = qh + ((size_t)bh * SEQ + q0 + a * 16 + r) * DKH + qd * 8;
        qf[a][0] = *(const v8bf*)qp;
        qf[a][1] = *(const v8bf*)(qp + 32);
    }

    v4f oacc[2][4] = {};
    float lsum[2] = {0.f, 0.f};

    const __bf16* kp0 = kbh + (size_t)r * DKH + qd * 8;
    const _Float16* vp0 = vbh + (size_t)r * SEQ + qd * 8;

    // stage 0 loads (key block 0)
    v8bf kf[4];
    v8h vv[4];
    kf[0] = *(const v8bf*)kp0;
    kf[1] = *(const v8bf*)(kp0 + 32);
    kf[2] = *(const v8bf*)(kp0 + 16 * DKH);
    kf[3] = *(const v8bf*)(kp0 + 16 * DKH + 32);
#pragma unroll
    for (int g = 0; g < 4; ++g)
        vv[g] = *(const v8h*)(vp0 + (size_t)g * 16 * SEQ);

    for (int k0 = 0; k0 < SEQ; k0 += 32) {
        // prefetch next key block (wraps to 0 on last iter; values unused)
        const int kn = (k0 + 32) & (SEQ - 1);
        const __bf16* kp = kp0 + (size_t)kn * DKH;
        const _Float16* vp = vp0 + kn;
        v8bf kf2[4];
        v8h vv2[4];
        kf2[0] = *(const v8bf*)kp;
        kf2[1] = *(const v8bf*)(kp + 32);
        kf2[2] = *(const v8bf*)(kp + 16 * DKH);
        kf2[3] = *(const v8bf*)(kp + 16 * DKH + 32);
#pragma unroll
        for (int g = 0; g < 4; ++g)
            vv2[g] = *(const v8h*)(vp + (size_t)g * 16 * SEQ);

        // S^T = K.Q^T, exp2 in-register -> P^T fragments
        v4h pf[2][2]; // [kg][a]
#pragma unroll
        for (int kg = 0; kg < 2; ++kg)
#pragma unroll
            for (int a = 0; a < 2; ++a) {
                v4f s = mfma16x32(kf[kg * 2], qf[a][0], v4f{});
                s = mfma16x32(kf[kg * 2 + 1], qf[a][1], s);
                float tsum = 0.f;
#pragma unroll
                for (int i = 0; i < 4; ++i) {
                    float p = __builtin_exp2f(s[i]);
                    pf[kg][a][i] = (_Float16)p;
                    tsum += p;
                }
                lsum[a] += tsum;
            }

        // O^T += V^T . P^T  (vv lo half = kg0 frag, hi half = kg1 frag)
#pragma unroll
        for (int g = 0; g < 4; ++g) {
            v4h vlo = __builtin_shufflevector(vv[g], vv[g], 0, 1, 2, 3);
            v4h vhi = __builtin_shufflevector(vv[g], vv[g], 4, 5, 6, 7);
#pragma unroll
            for (int a = 0; a < 2; ++a) {
                oacc[a][g] = mfma16x16h(vlo, pf[0][a], oacc[a][g]);
                oacc[a][g] = mfma16x16h(vhi, pf[1][a], oacc[a][g]);
            }
        }
#pragma unroll
        for (int j = 0; j < 4; ++j) { kf[j] = kf2[j]; vv[j] = vv2[j]; }
    }

    const int b = bh >> 4, h = bh & (NHEADS - 1);
#pragma unroll
    for (int a = 0; a < 2; ++a) {
        float u = lsum[a];
        u += __shfl_xor(u, 16);
        u += __shfl_xor(u, 32);
        float inv = 1.0f / u;
        int l = q0 + a * 16 + r;
        __bf16* op = oh + (((size_t)(b * SEQ + l)) * NHEADS + h) * DKH + qd * 4;
#pragma unroll
        for (int g = 0; g < 4; ++g) {
            v4bf ov;
#pragma unroll
            for (int i = 0; i < 4; ++i) ov[i] = (__bf16)(oacc[a][g][i] * inv);
            *(v4bf*)(op + g * 16) = ov;
        }
    }
}

extern "C" void kernel_launch(void* const* d_in, const int* in_sizes, int n_in,
                              void* d_out, int out_size, void* d_ws, size_t ws_size,
                              hipStream_t stream) {
    const float* Q = (const float*)d_in[0];
    const float* K = (const float*)d_in[1];
    const float* V = (const float*)d_in[2];
    const float* WQ = (const float*)d_in[3];
    const float* WK = (const float*)d_in[4];
    const float* WV = (const float*)d_in[5];
    const float* WO = (const float*)d_in[6];
    float* out = (float*)d_out;

    const size_t elems = (size_t)M_TOT * D_MODEL;
    const size_t welems = (size_t)D_MODEL * D_MODEL;
    __bf16* wb = (__bf16*)d_ws;               // [4][1024*1024] bf16 weights
    __bf16* qh = wb + 4 * welems;             // [b,h,l,dk]
    __bf16* kh = qh + elems;                  // [b,h,l,dk]
    _Float16* vtb = (_Float16*)(kh + elems);  // [b,h,dk,l] f16, key-permuted
    __bf16* oh = (__bf16*)(vtb + elems);      // [b,l,h,dk]

    cvt_w<<<2048, 256, 0, stream>>>(WQ, WK, WV, WO, wb);
    gemm_qkv<<<dim3(M_TOT / 128, D_MODEL / 128, 3), 256, 0, stream>>>(Q, K, V, wb, qh, kh, vtb);
    attn_kernel<<<1024, 256, 0, stream>>>(qh, kh, vtb, oh);
    gemm_out<<<dim3(M_TOT / 128, D_MODEL / 128), 256, 0, stream>>>(oh, wb + 3 * welems, out);
}

// Round 6
// 377.375 us; speedup vs baseline: 1.3236x; 1.3236x over previous
//
#include <hip/hip_runtime.h>
#include <stdint.h>

// MultiHeadAttention  b=4, L=2048, d=1024, H=16, dk=64. I/O fp32; bf16/f16 MFMA inside.
#define D_MODEL 1024
#define NHEADS 16
#define DKH 64
#define SEQ 2048
#define BATCH 4
#define M_TOT (BATCH * SEQ) // 8192
#define LOG2E 1.44269504088896340736f

typedef __bf16 v8bf __attribute__((ext_vector_type(8)));
typedef __bf16 v4bf __attribute__((ext_vector_type(4)));
typedef _Float16 v8h __attribute__((ext_vector_type(8)));
typedef _Float16 v4h __attribute__((ext_vector_type(4)));
typedef float v4f __attribute__((ext_vector_type(4)));

typedef const __attribute__((address_space(1))) void* gas_ptr;
typedef __attribute__((address_space(3))) void* las_ptr;

static __device__ __forceinline__ void async16(const void* g, void* l) {
    __builtin_amdgcn_global_load_lds((gas_ptr)g, (las_ptr)l, 16, 0, 0);
}

static __device__ __forceinline__ v4f mfma16x32(v8bf a, v8bf b, v4f c) {
    // D(16x16)=A(16x32)*B(32x16)+C. A: m=l&15,k=(l>>4)*8+j. B: k=(l>>4)*8+j,n=l&15.
    // D: col=l&15, row=(l>>4)*4+reg.   (verified R2-R5)
    return __builtin_amdgcn_mfma_f32_16x16x32_bf16(a, b, c, 0, 0, 0);
}
static __device__ __forceinline__ v4f mfma16x16h(v4h a, v4h b, v4f c) {
    // D(16x16)=A(16x16)*B(16x16)+C. A: m=l&15,k=(l>>4)*4+j. B: k=(l>>4)*4+j,n=l&15.
    return __builtin_amdgcn_mfma_f32_16x16x16f16(a, b, c, 0, 0, 0);
}

// fp32 -> bf16, 8 elements/thread
__global__ __launch_bounds__(256) void cvt_x(const float* __restrict__ src,
                                             __bf16* __restrict__ dst) {
    int i = blockIdx.x * 256 + threadIdx.x;
    const float4* s = (const float4*)src;
    float4 a = s[2 * i], b = s[2 * i + 1];
    v8bf o;
    o[0] = (__bf16)a.x; o[1] = (__bf16)a.y; o[2] = (__bf16)a.z; o[3] = (__bf16)a.w;
    o[4] = (__bf16)b.x; o[5] = (__bf16)b.y; o[6] = (__bf16)b.z; o[7] = (__bf16)b.w;
    *(v8bf*)(dst + (size_t)i * 8) = o;
}

// Convert 4 fp32 weight matrices to packed bf16 [4][1024*1024]
__global__ __launch_bounds__(256) void cvt_w(const float* __restrict__ w0,
                                             const float* __restrict__ w1,
                                             const float* __restrict__ w2,
                                             const float* __restrict__ w3,
                                             __bf16* __restrict__ dst) {
    int gid = blockIdx.x * 256 + threadIdx.x;
    int tsel = gid >> 17;
    int off = gid & 131071;
    const float* s = (tsel == 0) ? w0 : (tsel == 1) ? w1 : (tsel == 2) ? w2 : w3;
    const float4* sp = (const float4*)s + 2 * (size_t)off;
    float4 a = sp[0], b = sp[1];
    v8bf o;
    o[0] = (__bf16)a.x; o[1] = (__bf16)a.y; o[2] = (__bf16)a.z; o[3] = (__bf16)a.w;
    o[4] = (__bf16)b.x; o[5] = (__bf16)b.y; o[6] = (__bf16)b.z; o[7] = (__bf16)b.w;
    *(v8bf*)(dst + ((size_t)tsel << 20) + (size_t)off * 8) = o;
}

// m97-style NT GEMM: C = scale * A.W^T, A bf16 [8192][1024], W bf16 [1024][1024].
// Both operands async16-staged, 128x128 tile, BK=32. Epilogues:
// LAYOUT 0: fp32 row-major [M][1024]   (final output)
// LAYOUT 1: bf16 head-major [b,h,l,dk] (q, k)
// LAYOUT 2: f16 transposed+key-permuted [b,h,dk,pos] (v)
template <int LAYOUT>
__global__ __launch_bounds__(256) void gemm_nt(const __bf16* __restrict__ A,
                                               const __bf16* __restrict__ W,
                                               void* __restrict__ Cv, float scale) {
    const int t = threadIdx.x, lane = t & 63, wave = t >> 6;
    const int r = lane & 15, qd = lane >> 4;
    const int m0 = blockIdx.x * 128, n0 = blockIdx.y * 128;
    const int mw = (wave & 1) * 64, nw = (wave >> 1) * 64;

    __shared__ __align__(16) __bf16 As[128 * 32];
    __shared__ __align__(16) __bf16 Bs[128 * 32];

    const int wc = (lane & 3) ^ ((lane >> 3) & 3);
    const int wrow = lane >> 2;
    const int rdpos = (qd ^ ((r >> 1) & 3)) * 8;

    v4f acc[4][4] = {};
    for (int k0 = 0; k0 < D_MODEL; k0 += 32) {
#pragma unroll
        for (int p = 0; p < 2; ++p) {
            int rb = (p * 4 + wave) * 16;
            async16(A + (size_t)(m0 + rb + wrow) * D_MODEL + k0 + wc * 8, &As[rb * 32]);
            async16(W + (size_t)(n0 + rb + wrow) * D_MODEL + k0 + wc * 8, &Bs[rb * 32]);
        }
        __syncthreads();
        v8bf af[4], bfr[4];
#pragma unroll
        for (int mt = 0; mt < 4; ++mt)
            af[mt] = *(const v8bf*)&As[(mw + mt * 16 + r) * 32 + rdpos];
#pragma unroll
        for (int nt = 0; nt < 4; ++nt)
            bfr[nt] = *(const v8bf*)&Bs[(nw + nt * 16 + r) * 32 + rdpos];
#pragma unroll
        for (int mt = 0; mt < 4; ++mt)
#pragma unroll
            for (int nt = 0; nt < 4; ++nt)
                acc[mt][nt] = mfma16x32(af[mt], bfr[nt], acc[mt][nt]);
        __syncthreads();
    }

#pragma unroll
    for (int mt = 0; mt < 4; ++mt)
#pragma unroll
        for (int nt = 0; nt < 4; ++nt) {
            int row = m0 + mw + mt * 16 + qd * 4;
            int col = n0 + nw + nt * 16 + r;
            if (LAYOUT == 0) {
                float* C = (float*)Cv;
#pragma unroll
                for (int i = 0; i < 4; ++i)
                    C[(size_t)(row + i) * D_MODEL + col] = acc[mt][nt][i];
            } else {
                int bb = row >> 11, l = row & (SEQ - 1);
                int h = col >> 6, d = col & (DKH - 1);
                if (LAYOUT == 2) {
                    // permuted key position: pos = (l&~31) + quad*8 + half*4 + off
                    int pos = (l & ~31) + (((l >> 2) & 3) << 3) + (((l >> 4) & 1) << 2);
                    _Float16* vt = (_Float16*)Cv;
                    v4h o;
#pragma unroll
                    for (int i = 0; i < 4; ++i) o[i] = (_Float16)acc[mt][nt][i];
                    *(v4h*)&vt[((size_t)((bb * NHEADS + h) * DKH + d)) * SEQ + pos] = o;
                } else {
                    __bf16* dst = (__bf16*)Cv;
#pragma unroll
                    for (int i = 0; i < 4; ++i)
                        dst[(((size_t)(bb * NHEADS + h) * SEQ) + l + i) * DKH + d] =
                            (__bf16)(acc[mt][nt][i] * scale);
                }
            }
        }
}

// Attention: 512 blocks (XCD swizzle: 8 bh/XCD), 4 waves x 64 queries = 256 q/block.
// K (bf16) + permuted V^T (f16) staged in double-buffered 64-key LDS tiles via
// async16 (shared by all 4 waves -> 4x less L1/L2 traffic than R5). Prefetch for
// buf^1 issued right after the barrier; a full stage of compute separates issue
// from the barrier drain. lsum via ones-MFMA (column sums in C-layout, no VALU
// adds, no shuffle reduction).
__global__ __launch_bounds__(256, 2) void attn_kernel(const __bf16* __restrict__ qh,
                                                      const __bf16* __restrict__ kh,
                                                      const _Float16* __restrict__ vt,
                                                      __bf16* __restrict__ oh) {
    const int lane = threadIdx.x & 63, wave = threadIdx.x >> 6;
    const int r = lane & 15, qd = lane >> 4;
    const int id = blockIdx.x;
    const int bh = (id & 7) * 8 + ((id >> 3) & 7); // 8 bh per XCD
    const int q0 = (id >> 6) * 256 + wave * 64;

    __shared__ __align__(16) __bf16 Kb[2][64 * 64];
    __shared__ __align__(16) _Float16 Vb[2][64 * 64];

    const __bf16* kbh = kh + (size_t)bh * SEQ * DKH;
    const _Float16* vbh = vt + (size_t)bh * DKH * SEQ;

    v8bf qf[4][2];
#pragma unroll
    for (int a = 0; a < 4; ++a) {
        const __bf16* qp = qh + ((size_t)bh * SEQ + q0 + a * 16 + r) * DKH + qd * 8;
        qf[a][0] = *(const v8bf*)qp;
        qf[a][1] = *(const v8bf*)(qp + 32);
    }

    v4f oacc[4][4] = {};
    v4f psum[4] = {};
    v4h ones;
    ones[0] = (_Float16)1.f; ones[1] = (_Float16)1.f;
    ones[2] = (_Float16)1.f; ones[3] = (_Float16)1.f;

    // staging map: wave covers rows wave*16..+15 in 2 passes of 8 rows; 128B rows = 8 chunks
    const int srow = lane >> 3;
    const int sc = (lane & 7) ^ srow; // swizzled source chunk (dest pos = lane&7)
    const int rs = r & 7;

#pragma unroll
    for (int p = 0; p < 2; ++p) {
        int rb = wave * 16 + p * 8;
        async16(kbh + (size_t)(rb + srow) * DKH + sc * 8, &Kb[0][rb * 64]);
        async16(vbh + (size_t)(rb + srow) * SEQ + sc * 8, &Vb[0][rb * 64]);
    }

    for (int tt = 0; tt < SEQ / 64; ++tt) {
        const int buf = tt & 1;
        __syncthreads(); // buf staged; all waves done reading buf^1
        if (tt + 1 < SEQ / 64) {
            const int t0 = (tt + 1) * 64;
#pragma unroll
            for (int p = 0; p < 2; ++p) {
                int rb = wave * 16 + p * 8;
                async16(kbh + (size_t)(t0 + rb + srow) * DKH + sc * 8, &Kb[buf ^ 1][rb * 64]);
                async16(vbh + (size_t)(rb + srow) * SEQ + t0 + sc * 8, &Vb[buf ^ 1][rb * 64]);
            }
        }
        const __bf16* Kc = Kb[buf];
        const _Float16* Vc = Vb[buf];
#pragma unroll
        for (int kb = 0; kb < 2; ++kb) {
            v4h pf[2][4]; // [kg][a]
#pragma unroll
            for (int kg = 0; kg < 2; ++kg) {
                int row = kb * 32 + kg * 16 + r;
                v8bf ka = *(const v8bf*)&Kc[row * 64 + (qd ^ rs) * 8];
                v8bf kc = *(const v8bf*)&Kc[row * 64 + ((qd + 4) ^ rs) * 8];
#pragma unroll
                for (int a = 0; a < 4; ++a) {
                    v4f s = mfma16x32(ka, qf[a][0], v4f{});
                    s = mfma16x32(kc, qf[a][1], s);
#pragma unroll
                    for (int i = 0; i < 4; ++i)
                        pf[kg][a][i] = (_Float16)__builtin_exp2f(s[i]);
                }
            }
#pragma unroll
            for (int a = 0; a < 4; ++a) {
                psum[a] = mfma16x16h(ones, pf[0][a], psum[a]);
                psum[a] = mfma16x16h(ones, pf[1][a], psum[a]);
            }
#pragma unroll
            for (int g = 0; g < 4; ++g) {
                v8h vv = *(const v8h*)&Vc[(g * 16 + r) * 64 + ((kb * 4 + qd) ^ rs) * 8];
                v4h vlo = __builtin_shufflevector(vv, vv, 0, 1, 2, 3);
                v4h vhi = __builtin_shufflevector(vv, vv, 4, 5, 6, 7);
#pragma unroll
                for (int a = 0; a < 4; ++a) {
                    oacc[a][g] = mfma16x16h(vlo, pf[0][a], oacc[a][g]);
                    oacc[a][g] = mfma16x16h(vhi, pf[1][a], oacc[a][g]);
                }
            }
        }
    }

    const int b = bh >> 4, h = bh & (NHEADS - 1);
#pragma unroll
    for (int a = 0; a < 4; ++a) {
        float inv = 1.0f / psum[a][0]; // column sum replicated across rows
        int l = q0 + a * 16 + r;
        __bf16* op = oh + (((size_t)(b * SEQ + l)) * NHEADS + h) * DKH + qd * 4;
#pragma unroll
        for (int g = 0; g < 4; ++g) {
            v4bf ov;
#pragma unroll
            for (int i = 0; i < 4; ++i) ov[i] = (__bf16)(oacc[a][g][i] * inv);
            *(v4bf*)(op + g * 16) = ov;
        }
    }
}

extern "C" void kernel_launch(void* const* d_in, const int* in_sizes, int n_in,
                              void* d_out, int out_size, void* d_ws, size_t ws_size,
                              hipStream_t stream) {
    const float* Q = (const float*)d_in[0];
    const float* K = (const float*)d_in[1];
    const float* V = (const float*)d_in[2];
    const float* WQ = (const float*)d_in[3];
    const float* WK = (const float*)d_in[4];
    const float* WV = (const float*)d_in[5];
    const float* WO = (const float*)d_in[6];
    float* out = (float*)d_out;

    const size_t elems = (size_t)M_TOT * D_MODEL;    // 8.4M
    const size_t welems = (size_t)D_MODEL * D_MODEL; // 1.05M
    __bf16* wb = (__bf16*)d_ws;               // [4][1024*1024] bf16 weights (8 MB)
    __bf16* xb = wb + 4 * welems;             // staged bf16 activation (16 MB, reused)
    __bf16* qh = xb + elems;                  // [b,h,l,dk]
    __bf16* kh = qh + elems;                  // [b,h,l,dk]
    _Float16* vtb = (_Float16*)(kh + elems);  // [b,h,dk,l] f16, key-permuted
    __bf16* oh = (__bf16*)(vtb + elems);      // [b,l,h,dk]

    dim3 gg(M_TOT / 128, D_MODEL / 128);

    cvt_w<<<2048, 256, 0, stream>>>(WQ, WK, WV, WO, wb);
    cvt_x<<<4096, 256, 0, stream>>>(Q, xb);
    gemm_nt<1><<<gg, 256, 0, stream>>>(xb, wb, qh, 0.125f * LOG2E);
    cvt_x<<<4096, 256, 0, stream>>>(K, xb);
    gemm_nt<1><<<gg, 256, 0, stream>>>(xb, wb + welems, kh, 1.0f);
    cvt_x<<<4096, 256, 0, stream>>>(V, xb);
    gemm_nt<2><<<gg, 256, 0, stream>>>(xb, wb + 2 * welems, vtb, 1.0f);
    attn_kernel<<<512, 256, 0, stream>>>(qh, kh, vtb, oh);
    gemm_nt<0><<<gg, 256, 0, stream>>>(oh, wb + 3 * welems, out, 1.0f);
}